// Round 2
// baseline (15444.661 us; speedup 1.0000x reference)
//
#include <hip/hip_runtime.h>
#include <cstdint>
#include <cstddef>

#define D16 16
#define NCLS 16
#define NPTS 20000
#define UTD 136
#define NSWEEP 6
#define SSCL (0.5f / 32.0f)  // sym*0.5 * 2^-5 scaling for sigma expm

// ---------------- workspace layout (float offsets), total ~2.3 MB ----------
static constexpr size_t WS_SQRTX  = 0;                               // 16*256
static constexpr size_t WS_ISQRTX = WS_SQRTX  + (size_t)NCLS * 256;  // 16*256
static constexpr size_t WS_T0     = WS_ISQRTX + (size_t)NCLS * 256;  // 16*136*136
static constexpr size_t WS_T1     = WS_T0 + (size_t)NCLS * UTD * UTD;

__device__ __forceinline__ float fast_rcp(float x) { return __builtin_amdgcn_rcpf(x); }
__device__ __forceinline__ float fast_rsq(float x) { return __builtin_amdgcn_rsqf(x); }

// =================================================================
// P0: per-class sqrt_x = expm(+S/2), inv_sqrt_x = expm(-S/2),
//     S = sym(means_c). Scaling-squaring Taylor: k=3, degree 6.
// One block, 16 lane-groups of 16 (one class per group).
// =================================================================
__global__ __launch_bounds__(256) void prep_means_kernel(const float* __restrict__ means,
                                                         float* __restrict__ sqrtx,
                                                         float* __restrict__ isqrtx) {
  __shared__ float Tl[16 * 260];
  const int tid = threadIdx.x;
  const int g = tid >> 4;   // class
  const int j = tid & 15;   // row
  float s[16];
#pragma unroll
  for (int k = 0; k < 16; ++k) {
    float mjk = means[g * 256 + j * 16 + k];
    float mkj = means[g * 256 + k * 16 + j];
    // sym * 0.5 (for sqrt) * 2^-3 scaling
    s[k] = (mjk + mkj) * (0.5f * 0.5f * 0.125f);
  }
#pragma unroll
  for (int sgn = 0; sgn < 2; ++sgn) {
    float t[16];
#pragma unroll
    for (int i = 0; i < 16; ++i) t[i] = (i == j) ? 1.0f : 0.0f;
    // Horner: for it = 6..1 : T = S*T/it + I
#pragma unroll
    for (int it = 6; it >= 1; --it) {
      __syncthreads();
#pragma unroll
      for (int i = 0; i < 16; ++i) Tl[g * 260 + j * 16 + i] = t[i];
      __syncthreads();
      float acc[16];
#pragma unroll
      for (int i = 0; i < 16; ++i) acc[i] = 0.f;
#pragma unroll
      for (int k = 0; k < 16; ++k) {
        float sk = s[k];
#pragma unroll
        for (int i = 0; i < 16; ++i) acc[i] = fmaf(sk, Tl[g * 260 + k * 16 + i], acc[i]);
      }
      const float r = 1.0f / (float)it;  // compile-time constant (unrolled)
#pragma unroll
      for (int i = 0; i < 16; ++i) t[i] = fmaf(acc[i], r, (i == j) ? 1.0f : 0.0f);
    }
    // 3 squarings
#pragma unroll
    for (int sq = 0; sq < 3; ++sq) {
      __syncthreads();
#pragma unroll
      for (int i = 0; i < 16; ++i) Tl[g * 260 + j * 16 + i] = t[i];
      __syncthreads();
      float acc[16];
#pragma unroll
      for (int i = 0; i < 16; ++i) acc[i] = 0.f;
#pragma unroll
      for (int k = 0; k < 16; ++k) {
        float tk = t[k];
#pragma unroll
        for (int i = 0; i < 16; ++i) acc[i] = fmaf(tk, Tl[g * 260 + k * 16 + i], acc[i]);
      }
#pragma unroll
      for (int i = 0; i < 16; ++i) t[i] = acc[i];
    }
    float* dst = (sgn == 0) ? sqrtx : isqrtx;
#pragma unroll
    for (int i = 0; i < 16; ++i) dst[g * 256 + j * 16 + i] = t[i];
#pragma unroll
    for (int k = 0; k < 16; ++k) s[k] = -s[k];
  }
}

// =================================================================
// 136x136 expm of X = sym(sigma_c)*2^-5, Taylor-6 Horner + 5 squarings.
// sym is computed on the fly from sigma (saves 2 ws buffers).
// =================================================================

// T = X/6 + I
__global__ __launch_bounds__(256) void expm_init_kernel(const float* __restrict__ sig,
                                                        float* __restrict__ T) {
  const int c = blockIdx.y, rb = blockIdx.x;
  const size_t base = (size_t)c * UTD * UTD;
  for (int e = threadIdx.x; e < 17 * UTD; e += 256) {
    int r = e / UTD, col = e - r * UTD;
    int i = rb * 17 + r;
    float x = (sig[base + (size_t)i * UTD + col] + sig[base + (size_t)col * UTD + i]) * SSCL;
    T[base + (size_t)i * UTD + col] = fmaf(x, (1.0f / 6.0f), (i == col) ? 1.0f : 0.0f);
  }
}

// mode 0: Tout = X*Tin*coef + I  (coef = SSCL/j, X-scale folded into coef)
// mode 1: Tout = Tin*Tin
__global__ __launch_bounds__(256) void expm_stage_kernel(const float* __restrict__ sig,
                                                         const float* __restrict__ Tin,
                                                         float* __restrict__ Tout,
                                                         float coef, int mode) {
  const int c = blockIdx.y, rb = blockIdx.x;
  const size_t base = (size_t)c * UTD * UTD;
  const float* S = sig + base;
  const float* B = Tin + base;
  float* O = Tout + base;
  for (int e = threadIdx.x; e < 17 * UTD; e += 256) {
    int r = e / UTD, col = e - r * UTD;
    int i = rb * 17 + r;
    float acc = 0.f;
    if (mode) {
      const float* arow = B + (size_t)i * UTD;
#pragma unroll 4
      for (int k = 0; k < UTD; ++k) acc = fmaf(arow[k], B[(size_t)k * UTD + col], acc);
      O[(size_t)i * UTD + col] = acc;
    } else {
      const float* srow = S + (size_t)i * UTD;
#pragma unroll 4
      for (int k = 0; k < UTD; ++k)
        acc = fmaf(srow[k] + S[(size_t)k * UTD + i], B[(size_t)k * UTD + col], acc);
      O[(size_t)i * UTD + col] = fmaf(acc, coef, (i == col) ? 1.0f : 0.0f);
    }
  }
}

// Permute Sig from reference triu (row-major) order to our column-triu order:
// ours(i,j; i<=j) = j(j+1)/2 + i   <->  ref(i,j) = i*16 - i(i-1)/2 + (j-i)
__global__ __launch_bounds__(256) void permute_sig_kernel(const float* __restrict__ Sin,
                                                          float* __restrict__ Sigp) {
  __shared__ int perm[UTD];
  if (threadIdx.x < UTD) {
    int t = threadIdx.x;
    int jj = 0;
    while ((jj + 1) * (jj + 2) / 2 <= t) ++jj;
    int i = t - jj * (jj + 1) / 2;
    perm[t] = i * D16 - i * (i - 1) / 2 + (jj - i);
  }
  __syncthreads();
  const int c = blockIdx.y, rb = blockIdx.x;
  const size_t base = (size_t)c * UTD * UTD;
  for (int e = threadIdx.x; e < 17 * UTD; e += 256) {
    int r = e / UTD, col = e - r * UTD;
    int a = rb * 17 + r;
    Sigp[base + (size_t)a * UTD + col] = Sin[base + (size_t)perm[a] * UTD + perm[col]];
  }
}

// =================================================================
// Main kernel. Block = 256 thr = 4 waves = 16 matrices (16 consecutive
// n, one class c). Lane j of matrix `mat` owns column j of M (registers)
// and row j of R = sqrt_x * V (registers). Jacobi exchanges via per-wave
// LDS regions — NO block barrier in the hot loop (all intra-wave).
// Column region stride: 18 per column, 291 per matrix (291 % 32 == 3 so
// mats {0,2} use even banks, {1,3} odd banks -> only free 2-way aliasing).
// =================================================================
#define SM_AL 0        // 16 * 291
#define SM_CSL 4656    // 16*17 float2 (c,s per pair)
#define SM_LWL 5200    // 16*20 log-eigenvalues
#define SM_VL 5520     // 16*140 v vectors (column-triu order)
#define SM_PDL 7760    // 16*16 dist partials
#define SM_BL 8016     // 256: inv_sqrt_x (class) staged
#define SM_TOT 8272    // 33088 B -> 4 blocks/CU by LDS

__global__ __launch_bounds__(256, 4) void spd_main_kernel(
    const float* __restrict__ feats, const float* __restrict__ sqrtx,
    const float* __restrict__ isqrtx, const float* __restrict__ Sigp,
    const float* __restrict__ bias, float* __restrict__ out) {
  __shared__ float sm[SM_TOT];
  const int tid = threadIdx.x;
  const int mat = tid >> 4;
  const int j = tid & 15;
  const int c = blockIdx.y;
  const int n0 = blockIdx.x * 16;
  const int n = n0 + mat;

  sm[SM_BL + tid] = isqrtx[(size_t)c * 256 + tid];
  __syncthreads();

  const int albase = SM_AL + mat * 291;

  // ---- load A row j vectorized (node_feats symmetric: row == column) ----
  float ar[16];
  {
    const float4* fp4 = (const float4*)(feats + ((size_t)n * 256 + j * 16));
#pragma unroll
    for (int q = 0; q < 4; ++q) {
      float4 f4 = fp4[q];
      ar[4 * q + 0] = f4.x; ar[4 * q + 1] = f4.y;
      ar[4 * q + 2] = f4.z; ar[4 * q + 3] = f4.w;
    }
  }
  // ---- T = A*B, row j (B = inv_sqrt_x, broadcast from LDS) ----
  float t[16];
#pragma unroll
  for (int i = 0; i < 16; ++i) t[i] = 0.f;
#pragma unroll
  for (int k = 0; k < 16; ++k) {
    float avk = ar[k];
#pragma unroll
    for (int i = 0; i < 16; ++i) t[i] = fmaf(avk, sm[SM_BL + k * 16 + i], t[i]);
  }
  float br[16];
#pragma unroll
  for (int k = 0; k < 16; ++k) br[k] = sm[SM_BL + j * 16 + k];
  // publish T rows (row layout, stride 16), intra-wave only
#pragma unroll
  for (int i = 0; i < 16; ++i) sm[albase + j * 16 + i] = t[i];
  // ---- M = B*T, row j ----
  float a[16];
#pragma unroll
  for (int i = 0; i < 16; ++i) a[i] = 0.f;
#pragma unroll
  for (int k = 0; k < 16; ++k) {
    float bk = br[k];
#pragma unroll
    for (int i = 0; i < 16; ++i) a[i] = fmaf(bk, sm[albase + k * 16 + i], a[i]);
  }
  // ---- R init: row j of sqrt_x  (accumulates R = sqrt_x * V) ----
  float v[16];
  {
    const float4* sp4 = (const float4*)(sqrtx + ((size_t)c * 256 + j * 16));
#pragma unroll
    for (int q = 0; q < 4; ++q) {
      float4 f4 = sp4[q];
      v[4 * q + 0] = f4.x; v[4 * q + 1] = f4.y;
      v[4 * q + 2] = f4.z; v[4 * q + 3] = f4.w;
    }
  }
  // publish M as columns (stride 18); own diagonal kept in closed form
#pragma unroll
  for (int i = 0; i < 16; ++i) sm[albase + j * 18 + i] = a[i];
  float dg = a[j];

  float2* csl = (float2*)(sm + SM_CSL);

#pragma unroll 1
  for (int sweep = 0; sweep < NSWEEP; ++sweep) {
#pragma unroll
    for (int mi = 1; mi <= 15; ++mi) {
      const int jm = j ^ mi;
      const int pmin = (j < jm) ? j : jm;
      const int qmax = (j < jm) ? jm : j;
      // publish own column + closed-form diagonal (overwrite slot j)
#pragma unroll
      for (int i = 0; i < 16; ++i) sm[albase + j * 18 + i] = a[i];
      sm[albase + j * 18 + j] = dg;
      // read partner column + canonical scalars (identical bits in both lanes)
      float pa[16];
#pragma unroll
      for (int i = 0; i < 16; ++i) pa[i] = sm[albase + jm * 18 + i];
      float pdg = sm[albase + jm * 18 + jm];
      float apq = sm[albase + qmax * 18 + pmin];
      float app = (j < jm) ? dg : pdg;
      float aqq = (j < jm) ? pdg : dg;
      // rotation (branch-free, NaN-safe)
      float den = 2.0f * apq;
      float aden = (fabsf(den) < 1e-30f) ? copysignf(1e-30f, den) : den;
      float tau = (aqq - app) * fast_rcp(aden);
      float tt = copysignf(1.0f, tau) * fast_rcp(fabsf(tau) + sqrtf(fmaf(tau, tau, 1.0f)));
      float cc = fast_rsq(fmaf(tt, tt, 1.0f));
      float ss = tt * cc;
      if (j < jm) csl[mat * 17 + j] = make_float2(cc, ss);
      // column mix: (A*J) col j
      float se = (j < jm) ? -ss : ss;
#pragma unroll
      for (int i = 0; i < 16; ++i) a[i] = fmaf(cc, a[i], se * pa[i]);
      // diagonal closed form
      dg = (j < jm) ? fmaf(-tt, apq, dg) : fmaf(tt, apq, dg);
      // row rotations J^T (all 8 pairs, compile-time indices) on a[] and R row
#pragma unroll
      for (int x = 0; x < 16; ++x) {
        const int q = x ^ mi;
        if (q > x) {
          float2 cs = csl[mat * 17 + x];
          float cp = cs.x, sp = cs.y;
          float ax = a[x], aq2 = a[q];
          a[x] = fmaf(cp, ax, -sp * aq2);
          a[q] = fmaf(sp, ax, cp * aq2);
          float vx = v[x], vq = v[q];
          v[x] = fmaf(cp, vx, -sp * vq);
          v[q] = fmaf(sp, vx, cp * vq);
        }
      }
    }
  }

  // ---- post: log_xu = R diag(log w) R^T ; v-vector in column-triu order ----
  float lw = __logf(dg);
  sm[SM_LWL + mat * 20 + j] = lw;
#pragma unroll
  for (int i = 0; i < 16; ++i) sm[albase + j * 16 + i] = v[i];  // R rows
  float p[16];
#pragma unroll
  for (int k = 0; k < 16; ++k) p[k] = v[k] * sm[SM_LWL + mat * 20 + k];
#pragma unroll
  for (int i = 0; i < 16; ++i) {
    float e = 0.f;
#pragma unroll
    for (int k = 0; k < 16; ++k) e = fmaf(sm[albase + i * 16 + k], p[k], e);
    if (i <= j) sm[SM_VL + mat * 140 + (j * (j + 1) / 2 + i)] = e;
  }
  __syncthreads();

  // ---- phase 2: dist = v^T Sigp v  (Sigp from L2, v from LDS) ----
  const int nl = tid & 15;
  const int strip = tid >> 4;
  const float* sg = Sigp + (size_t)c * UTD * UTD;
  const float4* vrow4 = (const float4*)(sm + SM_VL + nl * 140);
  float distp = 0.f;
  for (int u = strip; u < UTD; u += 16) {
    const float4* row4 = (const float4*)(sg + (size_t)u * UTD);
    float vu = sm[SM_VL + nl * 140 + u];
    float acc = 0.f;
#pragma unroll 2
    for (int w4 = 0; w4 < UTD / 4; ++w4) {
      float4 s4 = row4[w4];
      float4 v4 = vrow4[w4];
      acc = fmaf(s4.x, v4.x, acc);
      acc = fmaf(s4.y, v4.y, acc);
      acc = fmaf(s4.z, v4.z, acc);
      acc = fmaf(s4.w, v4.w, acc);
    }
    distp = fmaf(vu, acc, distp);
  }
  sm[SM_PDL + strip * 16 + nl] = distp;
  __syncthreads();
  if (tid < 16) {
    float ssum = 0.f;
#pragma unroll
    for (int k = 0; k < 16; ++k) ssum += sm[SM_PDL + k * 16 + tid];
    out[(size_t)(n0 + tid) * NCLS + c] = fmaf(-0.5f, ssum, bias[c]);
  }
}

// =================================================================
extern "C" void kernel_launch(void* const* d_in, const int* in_sizes, int n_in,
                              void* d_out, int out_size, void* d_ws, size_t ws_size,
                              hipStream_t stream) {
  (void)in_sizes; (void)n_in; (void)out_size; (void)ws_size;
  const float* feats = (const float*)d_in[0];
  const float* means = (const float*)d_in[1];
  const float* sigma = (const float*)d_in[2];
  const float* bias = (const float*)d_in[3];
  float* out = (float*)d_out;
  float* ws = (float*)d_ws;

  float* sqrtx = ws + WS_SQRTX;
  float* isqrtx = ws + WS_ISQRTX;
  float* T0 = ws + WS_T0;
  float* T1 = ws + WS_T1;

  prep_means_kernel<<<1, 256, 0, stream>>>(means, sqrtx, isqrtx);
  expm_init_kernel<<<dim3(8, NCLS), 256, 0, stream>>>(sigma, T0);
  float* cur = T0;
  float* oth = T1;
  const float rc[5] = {0.2f, 0.25f, 1.0f / 3.0f, 0.5f, 1.0f};
  for (int s = 0; s < 5; ++s) {  // Horner stages: T = X*T/j + I
    expm_stage_kernel<<<dim3(8, NCLS), 256, 0, stream>>>(sigma, cur, oth, rc[s] * SSCL, 0);
    float* tmp = cur; cur = oth; oth = tmp;
  }
  for (int s = 0; s < 5; ++s) {  // 5 squarings (2^5 scaling)
    expm_stage_kernel<<<dim3(8, NCLS), 256, 0, stream>>>(sigma, cur, oth, 0.f, 1);
    float* tmp = cur; cur = oth; oth = tmp;
  }
  permute_sig_kernel<<<dim3(8, NCLS), 256, 0, stream>>>(cur, oth);
  spd_main_kernel<<<dim3(NPTS / 16, NCLS), 256, 0, stream>>>(feats, sqrtx, isqrtx, oth, bias, out);
}

// Round 5
// 6476.482 us; speedup vs baseline: 2.3847x; 2.3847x over previous
//
#include <hip/hip_runtime.h>
#include <cstdint>
#include <cstddef>

#define D16 16
#define NCLS 16
#define NPTS 20000
#define UTD 136
#define NSWEEP 6
#define SSCL (0.5f / 32.0f)  // sym*0.5 * 2^-5 scaling for sigma expm

// ---------------- workspace layout (float offsets), total ~2.3 MB ----------
static constexpr size_t WS_SQRTX  = 0;                               // 16*256
static constexpr size_t WS_ISQRTX = WS_SQRTX  + (size_t)NCLS * 256;  // 16*256
static constexpr size_t WS_T0     = WS_ISQRTX + (size_t)NCLS * 256;  // 16*136*136
static constexpr size_t WS_T1     = WS_T0 + (size_t)NCLS * UTD * UTD;

__device__ __forceinline__ float fast_rcp(float x) { return __builtin_amdgcn_rcpf(x); }
__device__ __forceinline__ float fast_rsq(float x) { return __builtin_amdgcn_rsqf(x); }

// =================================================================
// P0: per-class sqrt_x = expm(+S/2), inv_sqrt_x = expm(-S/2),
//     S = sym(means_c). Scaling-squaring Taylor: k=3, degree 6.
// One block, 16 lane-groups of 16 (one class per group).
// =================================================================
__global__ __launch_bounds__(256) void prep_means_kernel(const float* __restrict__ means,
                                                         float* __restrict__ sqrtx,
                                                         float* __restrict__ isqrtx) {
  __shared__ float Tl[16 * 260];
  const int tid = threadIdx.x;
  const int g = tid >> 4;   // class
  const int j = tid & 15;   // row
  float s[16];
#pragma unroll
  for (int k = 0; k < 16; ++k) {
    float mjk = means[g * 256 + j * 16 + k];
    float mkj = means[g * 256 + k * 16 + j];
    // sym * 0.5 (for sqrt) * 2^-3 scaling
    s[k] = (mjk + mkj) * (0.5f * 0.5f * 0.125f);
  }
#pragma unroll
  for (int sgn = 0; sgn < 2; ++sgn) {
    float t[16];
#pragma unroll
    for (int i = 0; i < 16; ++i) t[i] = (i == j) ? 1.0f : 0.0f;
    // Horner: for it = 6..1 : T = S*T/it + I
#pragma unroll
    for (int it = 6; it >= 1; --it) {
      __syncthreads();
#pragma unroll
      for (int i = 0; i < 16; ++i) Tl[g * 260 + j * 16 + i] = t[i];
      __syncthreads();
      float acc[16];
#pragma unroll
      for (int i = 0; i < 16; ++i) acc[i] = 0.f;
#pragma unroll
      for (int k = 0; k < 16; ++k) {
        float sk = s[k];
#pragma unroll
        for (int i = 0; i < 16; ++i) acc[i] = fmaf(sk, Tl[g * 260 + k * 16 + i], acc[i]);
      }
      const float r = 1.0f / (float)it;  // compile-time constant (unrolled)
#pragma unroll
      for (int i = 0; i < 16; ++i) t[i] = fmaf(acc[i], r, (i == j) ? 1.0f : 0.0f);
    }
    // 3 squarings
#pragma unroll
    for (int sq = 0; sq < 3; ++sq) {
      __syncthreads();
#pragma unroll
      for (int i = 0; i < 16; ++i) Tl[g * 260 + j * 16 + i] = t[i];
      __syncthreads();
      float acc[16];
#pragma unroll
      for (int i = 0; i < 16; ++i) acc[i] = 0.f;
#pragma unroll
      for (int k = 0; k < 16; ++k) {
        float tk = t[k];
#pragma unroll
        for (int i = 0; i < 16; ++i) acc[i] = fmaf(tk, Tl[g * 260 + k * 16 + i], acc[i]);
      }
#pragma unroll
      for (int i = 0; i < 16; ++i) t[i] = acc[i];
    }
    float* dst = (sgn == 0) ? sqrtx : isqrtx;
#pragma unroll
    for (int i = 0; i < 16; ++i) dst[g * 256 + j * 16 + i] = t[i];
#pragma unroll
    for (int k = 0; k < 16; ++k) s[k] = -s[k];
  }
}

// =================================================================
// 136x136 expm of X = sym(sigma_c)*2^-5, Taylor-6 Horner + 5 squarings.
// sym is computed on the fly from sigma (saves 2 ws buffers).
// =================================================================

// T = X/6 + I
__global__ __launch_bounds__(256) void expm_init_kernel(const float* __restrict__ sig,
                                                        float* __restrict__ T) {
  const int c = blockIdx.y, rb = blockIdx.x;
  const size_t base = (size_t)c * UTD * UTD;
  for (int e = threadIdx.x; e < 17 * UTD; e += 256) {
    int r = e / UTD, col = e - r * UTD;
    int i = rb * 17 + r;
    float x = (sig[base + (size_t)i * UTD + col] + sig[base + (size_t)col * UTD + i]) * SSCL;
    T[base + (size_t)i * UTD + col] = fmaf(x, (1.0f / 6.0f), (i == col) ? 1.0f : 0.0f);
  }
}

// mode 0: Tout = X*Tin*coef + I  (coef = SSCL/j, X-scale folded into coef)
// mode 1: Tout = Tin*Tin
__global__ __launch_bounds__(256) void expm_stage_kernel(const float* __restrict__ sig,
                                                         const float* __restrict__ Tin,
                                                         float* __restrict__ Tout,
                                                         float coef, int mode) {
  const int c = blockIdx.y, rb = blockIdx.x;
  const size_t base = (size_t)c * UTD * UTD;
  const float* S = sig + base;
  const float* B = Tin + base;
  float* O = Tout + base;
  for (int e = threadIdx.x; e < 17 * UTD; e += 256) {
    int r = e / UTD, col = e - r * UTD;
    int i = rb * 17 + r;
    float acc = 0.f;
    if (mode) {
      const float* arow = B + (size_t)i * UTD;
#pragma unroll 4
      for (int k = 0; k < UTD; ++k) acc = fmaf(arow[k], B[(size_t)k * UTD + col], acc);
      O[(size_t)i * UTD + col] = acc;
    } else {
      const float* srow = S + (size_t)i * UTD;
#pragma unroll 4
      for (int k = 0; k < UTD; ++k)
        acc = fmaf(srow[k] + S[(size_t)k * UTD + i], B[(size_t)k * UTD + col], acc);
      O[(size_t)i * UTD + col] = fmaf(acc, coef, (i == col) ? 1.0f : 0.0f);
    }
  }
}

// Permute Sig from reference triu (row-major) order to our column-triu order:
// ours(i,j; i<=j) = j(j+1)/2 + i   <->  ref(i,j) = i*16 - i(i-1)/2 + (j-i)
__global__ __launch_bounds__(256) void permute_sig_kernel(const float* __restrict__ Sin,
                                                          float* __restrict__ Sigp) {
  __shared__ int perm[UTD];
  if (threadIdx.x < UTD) {
    int t = threadIdx.x;
    int jj = 0;
    while ((jj + 1) * (jj + 2) / 2 <= t) ++jj;
    int i = t - jj * (jj + 1) / 2;
    perm[t] = i * D16 - i * (i - 1) / 2 + (jj - i);
  }
  __syncthreads();
  const int c = blockIdx.y, rb = blockIdx.x;
  const size_t base = (size_t)c * UTD * UTD;
  for (int e = threadIdx.x; e < 17 * UTD; e += 256) {
    int r = e / UTD, col = e - r * UTD;
    int a = rb * 17 + r;
    Sigp[base + (size_t)a * UTD + col] = Sin[base + (size_t)perm[a] * UTD + perm[col]];
  }
}

// =================================================================
// Main kernel. Block = 256 thr = 4 waves = 16 matrices (16 consecutive
// n, one class c). Lane j of matrix `mat` owns column j of M (registers)
// and row j of R = sqrt_x * V (registers). Jacobi exchanges via per-wave
// LDS regions — NO block barrier in the hot loop (all intra-wave).
// Column region stride: 18 per column, 291 per matrix (291 % 32 == 3 so
// mats {0,2} use even banks, {1,3} odd banks -> only free 2-way aliasing).
// NOTE: plain __launch_bounds__(256) — a (256,4) min-waves attr made LLVM
// spill to VGPR=64 (53 GB scratch traffic, 15 ms). Do not re-add.
// =================================================================
#define SM_AL 0        // 16 * 291
#define SM_CSL 4656    // 16*17 float2 (c,s per pair)
#define SM_LWL 5200    // 16*20 log-eigenvalues
#define SM_VL 5520     // 16*140 v vectors (column-triu order)
#define SM_PDL 7760    // 16*16 dist partials
#define SM_BL 8016     // 256: inv_sqrt_x (class) staged
#define SM_TOT 8272    // 33088 B -> 4 blocks/CU by LDS

__global__ __launch_bounds__(256) void spd_main_kernel(
    const float* __restrict__ feats, const float* __restrict__ sqrtx,
    const float* __restrict__ isqrtx, const float* __restrict__ Sigp,
    const float* __restrict__ bias, float* __restrict__ out) {
  __shared__ float sm[SM_TOT];
  const int tid = threadIdx.x;
  const int mat = tid >> 4;
  const int j = tid & 15;
  const int c = blockIdx.y;
  const int n0 = blockIdx.x * 16;
  const int n = n0 + mat;

  sm[SM_BL + tid] = isqrtx[(size_t)c * 256 + tid];
  __syncthreads();

  const int albase = SM_AL + mat * 291;

  // ---- load A row j vectorized (node_feats symmetric: row == column) ----
  float ar[16];
  {
    const float4* fp4 = (const float4*)(feats + ((size_t)n * 256 + j * 16));
#pragma unroll
    for (int q = 0; q < 4; ++q) {
      float4 f4 = fp4[q];
      ar[4 * q + 0] = f4.x; ar[4 * q + 1] = f4.y;
      ar[4 * q + 2] = f4.z; ar[4 * q + 3] = f4.w;
    }
  }
  // ---- T = A*B, row j (B = inv_sqrt_x, broadcast from LDS) ----
  float t[16];
#pragma unroll
  for (int i = 0; i < 16; ++i) t[i] = 0.f;
#pragma unroll
  for (int k = 0; k < 16; ++k) {
    float avk = ar[k];
#pragma unroll
    for (int i = 0; i < 16; ++i) t[i] = fmaf(avk, sm[SM_BL + k * 16 + i], t[i]);
  }
  float br[16];
#pragma unroll
  for (int k = 0; k < 16; ++k) br[k] = sm[SM_BL + j * 16 + k];
  // publish T rows (row layout, stride 16), intra-wave only
#pragma unroll
  for (int i = 0; i < 16; ++i) sm[albase + j * 16 + i] = t[i];
  // ---- M = B*T, row j ----
  float a[16];
#pragma unroll
  for (int i = 0; i < 16; ++i) a[i] = 0.f;
#pragma unroll
  for (int k = 0; k < 16; ++k) {
    float bk = br[k];
#pragma unroll
    for (int i = 0; i < 16; ++i) a[i] = fmaf(bk, sm[albase + k * 16 + i], a[i]);
  }
  // ---- R init: row j of sqrt_x  (accumulates R = sqrt_x * V) ----
  float v[16];
  {
    const float4* sp4 = (const float4*)(sqrtx + ((size_t)c * 256 + j * 16));
#pragma unroll
    for (int q = 0; q < 4; ++q) {
      float4 f4 = sp4[q];
      v[4 * q + 0] = f4.x; v[4 * q + 1] = f4.y;
      v[4 * q + 2] = f4.z; v[4 * q + 3] = f4.w;
    }
  }
  // publish M as columns (stride 18); own diagonal kept in closed form
#pragma unroll
  for (int i = 0; i < 16; ++i) sm[albase + j * 18 + i] = a[i];
  float dg = a[j];

  float2* csl = (float2*)(sm + SM_CSL);

#pragma unroll 1
  for (int sweep = 0; sweep < NSWEEP; ++sweep) {
#pragma unroll
    for (int mi = 1; mi <= 15; ++mi) {
      const int jm = j ^ mi;
      const int pmin = (j < jm) ? j : jm;
      const int qmax = (j < jm) ? jm : j;
      // publish own column + closed-form diagonal (overwrite slot j)
#pragma unroll
      for (int i = 0; i < 16; ++i) sm[albase + j * 18 + i] = a[i];
      sm[albase + j * 18 + j] = dg;
      // partner scalars (identical bits in both lanes of the pair)
      float pdg = sm[albase + jm * 18 + jm];
      float apq = sm[albase + qmax * 18 + pmin];
      float app = (j < jm) ? dg : pdg;
      float aqq = (j < jm) ? pdg : dg;
      // rotation (branch-free, NaN-safe)
      float den = 2.0f * apq;
      float aden = (fabsf(den) < 1e-30f) ? copysignf(1e-30f, den) : den;
      float tau = (aqq - app) * fast_rcp(aden);
      float tt = copysignf(1.0f, tau) * fast_rcp(fabsf(tau) + sqrtf(fmaf(tau, tau, 1.0f)));
      float cc = fast_rsq(fmaf(tt, tt, 1.0f));
      float ss = tt * cc;
      if (j < jm) csl[mat * 17 + j] = make_float2(cc, ss);
      // column mix: (A*J) col j — partner column read fused from LDS
      // (no pa[16] buffer: keeps peak VGPR pressure under the 128 cliff)
      float se = (j < jm) ? -ss : ss;
#pragma unroll
      for (int i = 0; i < 16; ++i)
        a[i] = fmaf(cc, a[i], se * sm[albase + jm * 18 + i]);
      // diagonal closed form
      dg = (j < jm) ? fmaf(-tt, apq, dg) : fmaf(tt, apq, dg);
      // row rotations J^T (all 8 pairs, compile-time indices) on a[] and R row
#pragma unroll
      for (int x = 0; x < 16; ++x) {
        const int q = x ^ mi;
        if (q > x) {
          float2 cs = csl[mat * 17 + x];
          float cp = cs.x, sp = cs.y;
          float ax = a[x], aq2 = a[q];
          a[x] = fmaf(cp, ax, -sp * aq2);
          a[q] = fmaf(sp, ax, cp * aq2);
          float vx = v[x], vq = v[q];
          v[x] = fmaf(cp, vx, -sp * vq);
          v[q] = fmaf(sp, vx, cp * vq);
        }
      }
    }
  }

  // ---- post: log_xu = R diag(log w) R^T ; v-vector in column-triu order ----
  float lw = __logf(dg);
  sm[SM_LWL + mat * 20 + j] = lw;
#pragma unroll
  for (int i = 0; i < 16; ++i) sm[albase + j * 16 + i] = v[i];  // R rows
  float p[16];
#pragma unroll
  for (int k = 0; k < 16; ++k) p[k] = v[k] * sm[SM_LWL + mat * 20 + k];
#pragma unroll
  for (int i = 0; i < 16; ++i) {
    float e = 0.f;
#pragma unroll
    for (int k = 0; k < 16; ++k) e = fmaf(sm[albase + i * 16 + k], p[k], e);
    if (i <= j) sm[SM_VL + mat * 140 + (j * (j + 1) / 2 + i)] = e;
  }
  __syncthreads();

  // ---- phase 2: dist = v^T Sigp v  (Sigp from L2, v from LDS) ----
  const int nl = tid & 15;
  const int strip = tid >> 4;
  const float* sg = Sigp + (size_t)c * UTD * UTD;
  const float4* vrow4 = (const float4*)(sm + SM_VL + nl * 140);
  float distp = 0.f;
  for (int u = strip; u < UTD; u += 16) {
    const float4* row4 = (const float4*)(sg + (size_t)u * UTD);
    float vu = sm[SM_VL + nl * 140 + u];
    float acc = 0.f;
#pragma unroll 2
    for (int w4 = 0; w4 < UTD / 4; ++w4) {
      float4 s4 = row4[w4];
      float4 v4 = vrow4[w4];
      acc = fmaf(s4.x, v4.x, acc);
      acc = fmaf(s4.y, v4.y, acc);
      acc = fmaf(s4.z, v4.z, acc);
      acc = fmaf(s4.w, v4.w, acc);
    }
    distp = fmaf(vu, acc, distp);
  }
  sm[SM_PDL + strip * 16 + nl] = distp;
  __syncthreads();
  if (tid < 16) {
    float ssum = 0.f;
#pragma unroll
    for (int k = 0; k < 16; ++k) ssum += sm[SM_PDL + k * 16 + tid];
    out[(size_t)(n0 + tid) * NCLS + c] = fmaf(-0.5f, ssum, bias[c]);
  }
}

// =================================================================
extern "C" void kernel_launch(void* const* d_in, const int* in_sizes, int n_in,
                              void* d_out, int out_size, void* d_ws, size_t ws_size,
                              hipStream_t stream) {
  (void)in_sizes; (void)n_in; (void)out_size; (void)ws_size;
  const float* feats = (const float*)d_in[0];
  const float* means = (const float*)d_in[1];
  const float* sigma = (const float*)d_in[2];
  const float* bias = (const float*)d_in[3];
  float* out = (float*)d_out;
  float* ws = (float*)d_ws;

  float* sqrtx = ws + WS_SQRTX;
  float* isqrtx = ws + WS_ISQRTX;
  float* T0 = ws + WS_T0;
  float* T1 = ws + WS_T1;

  prep_means_kernel<<<1, 256, 0, stream>>>(means, sqrtx, isqrtx);
  expm_init_kernel<<<dim3(8, NCLS), 256, 0, stream>>>(sigma, T0);
  float* cur = T0;
  float* oth = T1;
  const float rc[5] = {0.2f, 0.25f, 1.0f / 3.0f, 0.5f, 1.0f};
  for (int s = 0; s < 5; ++s) {  // Horner stages: T = X*T/j + I
    expm_stage_kernel<<<dim3(8, NCLS), 256, 0, stream>>>(sigma, cur, oth, rc[s] * SSCL, 0);
    float* tmp = cur; cur = oth; oth = tmp;
  }
  for (int s = 0; s < 5; ++s) {  // 5 squarings (2^5 scaling)
    expm_stage_kernel<<<dim3(8, NCLS), 256, 0, stream>>>(sigma, cur, oth, 0.f, 1);
    float* tmp = cur; cur = oth; oth = tmp;
  }
  permute_sig_kernel<<<dim3(8, NCLS), 256, 0, stream>>>(cur, oth);
  spd_main_kernel<<<dim3(NPTS / 16, NCLS), 256, 0, stream>>>(feats, sqrtx, isqrtx, oth, bias, out);
}